// Round 2
// baseline (5256.820 us; speedup 1.0000x reference)
//
#include <hip/hip_runtime.h>

#define N_NODES 10000
#define N_EDGES 320000
#define HD      256

// ---------------------------------------------------------------------------
// ws layout (floats). STORE mode appends ea1 at the tail.
//   P_s  @ 0           [N,256]   x@We0a[0:512]      (alive to end in RECOMP)
//   P_d  @ 2,560,000   [N,256]   x@We0a[512:1024]
//   bufA @ 5,120,000   [N,256]   t1 -> P1s
//   bufB @ 7,680,000   [N,256]   x1
//   bufC @ 10,240,000  [N,256]   agg -> P1d
//   deg  @ 12,800,000  [N]
//   Wc   @ 12,810,000  [256,256] We1b@Wp1
//   bc   @ 12,875,536  [256]     be1b@Wp1 + bp1
//   ea1  @ 12,875,792  [E,256]   (STORE mode only)
// RECOMP need = 51,503,168 B ; STORE need = 379,183,168 B
// ---------------------------------------------------------------------------
#define OFF_PD   2560000
#define OFF_BA   5120000
#define OFF_BB   7680000
#define OFF_BC   10240000
#define OFF_DEG  12800000
#define OFF_WC   12810000
#define OFF_BCV  12875536
#define OFF_EA1  12875792
#define NEED_STORE_BYTES 379183168ULL

// ---------------------------------------------------------------------------
// node GEMM: C[M,256] = act( A1[M,K1]@W[0:K1] + (A2*scale)[M,K2]@W[K1:] + b )
// 64-row tile, 256 threads, acc[4][16], KC=32, static LDS 43KB.
// ---------------------------------------------------------------------------
__global__ __launch_bounds__(256)
void node_gemm(const float* __restrict__ A1, int K1,
               const float* __restrict__ A2, int K2,
               const float* __restrict__ scale,
               const float* __restrict__ W,
               const float* __restrict__ bias,
               float* __restrict__ C, int M, int act)
{
  __shared__ float sA[64*36];
  __shared__ float sB[32*256];
  __shared__ float sBias[256];
  const int tid = threadIdx.x;
  const int r0  = blockIdx.x * 64;
  if (bias) sBias[tid] = bias[tid];
  const int ty = tid >> 4, tx = tid & 15;

  float acc[4][16];
#pragma unroll
  for (int r = 0; r < 4; r++)
#pragma unroll
    for (int c = 0; c < 16; c++) acc[r][c] = 0.f;

  const int K    = K1 + K2;
  const int arow = tid >> 2;
  const int aks  = (tid & 3) * 8;
  const int gr_a = r0 + arow;

  for (int kb = 0; kb < K; kb += 32) {
    const float* Ap; int lda, koff; float sc = 1.0f;
    if (kb < K1) { Ap = A1; lda = K1; koff = kb; }
    else { Ap = A2; lda = K2; koff = kb - K1;
           if (scale) sc = scale[gr_a < M ? gr_a : M-1]; }
#pragma unroll
    for (int j = 0; j < 8; j += 4) {
      float4 v;
      if (gr_a < M) v = *(const float4*)&Ap[(long)gr_a*lda + koff + aks + j];
      else { v.x = v.y = v.z = v.w = 0.f; }
      v.x *= sc; v.y *= sc; v.z *= sc; v.w *= sc;
      *(float4*)&sA[arow*36 + aks + j] = v;
    }
#pragma unroll
    for (int j = 0; j < 8; j++) {
      int i = tid + 256*j, row = i >> 6, c4 = i & 63;
      *(float4*)&sB[row*HD + c4*4] = *(const float4*)&W[(long)(kb+row)*HD + c4*4];
    }
    __syncthreads();
#pragma unroll 4
    for (int kk = 0; kk < 32; kk++) {
      float a0 = sA[(ty*4+0)*36 + kk];
      float a1 = sA[(ty*4+1)*36 + kk];
      float a2 = sA[(ty*4+2)*36 + kk];
      float a3 = sA[(ty*4+3)*36 + kk];
#pragma unroll
      for (int c = 0; c < 16; c++) {
        float b = sB[kk*HD + tx + 16*c];
        acc[0][c] += a0*b; acc[1][c] += a1*b;
        acc[2][c] += a2*b; acc[3][c] += a3*b;
      }
    }
    __syncthreads();
  }

#pragma unroll
  for (int r = 0; r < 4; r++) {
    int gr = r0 + ty*4 + r;
    if (gr >= M) continue;
#pragma unroll
    for (int c = 0; c < 16; c++) {
      int col = tx + 16*c;
      float v = acc[r][c];
      if (bias) v += sBias[col];
      if (act)  v = fmaxf(v, 0.f);
      C[(long)gr*HD + col] = v;
    }
  }
}

// bc[j] = sum_k be1b[k]*Wp1[k,j] + bp1[j]   (1 block, 256 threads)
__global__ __launch_bounds__(256)
void bc_k(const float* __restrict__ be1b, const float* __restrict__ Wp1,
          const float* __restrict__ bp1, float* __restrict__ bc)
{
  const int j = threadIdx.x;
  float s = bp1[j];
  for (int k = 0; k < HD; k++) s += be1b[k] * Wp1[k*HD + j];
  bc[j] = s;
}

__global__ void rdeg_k(float* __restrict__ deg)
{
  int i = blockIdx.x*blockDim.x + threadIdx.x;
  if (i < N_NODES) deg[i] = 1.0f / fmaxf(deg[i], 1.0f);
}

// ---------------------------------------------------------------------------
// conv_in edge stage.  h0 = relu(Pxs[s]+Pxd[d]+ea@W6+b0);  ea1 = h0@We0b+b1
// atomics: agg[d] += ea1, deg[d] += 1.   64 edges/block, 512 threads.
// Static LDS 75KB -> 2 blocks/CU.
// ---------------------------------------------------------------------------
template<bool STORE>
__global__ __launch_bounds__(512)
void edge_conv_in(const int* __restrict__ ei, const float* __restrict__ eattr,
                  const float* __restrict__ Pxs, const float* __restrict__ Pxd,
                  const float* __restrict__ W6, const float* __restrict__ b0,
                  const float* __restrict__ We0b, const float* __restrict__ b1,
                  float* __restrict__ ea1, float* __restrict__ agg,
                  float* __restrict__ deg)
{
  __shared__ float sA[64*260];
  __shared__ float sB[8*256];
  __shared__ int   sDst[64];
  const int tid = threadIdx.x;
  const long e0 = (long)blockIdx.x * 64;
  const int* src = ei;
  const int* dst = ei + N_EDGES;

  // phase 1: h0 -> sA   (8 lanes/edge; col = 32*t + 4*q, conflict-aware)
  {
    const int el = tid >> 3, q = tid & 7;
    const long e = e0 + el;
    const int s = src[e], d = dst[e];
    if (q == 0) { sDst[el] = d; atomicAdd(&deg[d], 1.0f); }
    float eav[6];
#pragma unroll
    for (int k = 0; k < 6; k++) eav[k] = eattr[e*6 + k];
    const float* ps = Pxs + (long)s*HD;
    const float* pd = Pxd + (long)d*HD;
    float* sa = sA + el*260;
#pragma unroll
    for (int t = 0; t < 8; t++) {
      const int j = t*32 + q*4;
      float4 a = *(const float4*)(ps + j);
      float4 b = *(const float4*)(pd + j);
      float4 bb = *(const float4*)(b0 + j);
      float vx = a.x + b.x + bb.x;
      float vy = a.y + b.y + bb.y;
      float vz = a.z + b.z + bb.z;
      float vw = a.w + b.w + bb.w;
#pragma unroll
      for (int k = 0; k < 6; k++) {
        float4 w = *(const float4*)(W6 + k*HD + j);
        vx += eav[k]*w.x; vy += eav[k]*w.y;
        vz += eav[k]*w.z; vw += eav[k]*w.w;
      }
      float4 o;
      o.x = fmaxf(vx, 0.f); o.y = fmaxf(vy, 0.f);
      o.z = fmaxf(vz, 0.f); o.w = fmaxf(vw, 0.f);
      *(float4*)(sa + j) = o;
    }
  }
  __syncthreads();

  // GEMM: ea1 = h0 @ We0b   (KC=8, acc[4][8])
  const int ty = tid >> 5, tx = tid & 31;
  float acc[4][8];
#pragma unroll
  for (int r = 0; r < 4; r++)
#pragma unroll
    for (int c = 0; c < 8; c++) acc[r][c] = 0.f;

  for (int kb = 0; kb < HD; kb += 8) {
    { int row = tid >> 6, c4 = tid & 63;
      *(float4*)&sB[row*HD + c4*4] = *(const float4*)&We0b[(long)(kb+row)*HD + c4*4]; }
    __syncthreads();
#pragma unroll
    for (int kk = 0; kk < 8; kk++) {
      float a0 = sA[(ty*4+0)*260 + kb+kk];
      float a1 = sA[(ty*4+1)*260 + kb+kk];
      float a2 = sA[(ty*4+2)*260 + kb+kk];
      float a3 = sA[(ty*4+3)*260 + kb+kk];
#pragma unroll
      for (int c = 0; c < 8; c++) {
        float b = sB[kk*HD + tx + 32*c];
        acc[0][c] += a0*b; acc[1][c] += a1*b;
        acc[2][c] += a2*b; acc[3][c] += a3*b;
      }
    }
    __syncthreads();
  }

  float bv[8];
#pragma unroll
  for (int c = 0; c < 8; c++) bv[c] = b1[tx + 32*c];
#pragma unroll
  for (int r = 0; r < 4; r++) {
    const int el = ty*4 + r;
    const int d  = sDst[el];
    const long e = e0 + el;
#pragma unroll
    for (int c = 0; c < 8; c++) {
      const int col = tx + 32*c;
      float v = acc[r][c] + bv[c];
      if constexpr (STORE) ea1[e*HD + col] = v;
      atomicAdd(&agg[(long)d*HD + col], v);
    }
  }
}

// ---------------------------------------------------------------------------
// Fused conv[0] edge MLP + predictor (folded through the residual):
//   [RECOMP only] h0 = relu(Pxs[s]+Pxd[d]+ea@W6+b0);  ea1 = h0@We0b+be0b
//   h1  = relu(ea1@WeE + P1s[s] + P1d[d] + be1a)
//   t   = ea1@Wp1                       (register-resident)
//   z   = h1@Wc + t + bc       where Wc=We1b@Wp1, bc=be1b@Wp1+bp1
//   out = leaky_relu(z) @ Wp2 + bp2
// 64 edges/block, 512 threads, static LDS 150KB.
// ---------------------------------------------------------------------------
template<bool STORE>
__global__ __launch_bounds__(512)
void edge_pred(const int* __restrict__ ei,
               const float* __restrict__ ea1g,
               const float* __restrict__ eattr,
               const float* __restrict__ Pxs, const float* __restrict__ Pxd,
               const float* __restrict__ W6, const float* __restrict__ b0,
               const float* __restrict__ We0b, const float* __restrict__ be0b,
               const float* __restrict__ P1s, const float* __restrict__ P1d,
               const float* __restrict__ WeE, const float* __restrict__ be1a,
               const float* __restrict__ Wp1,
               const float* __restrict__ Wc,  const float* __restrict__ bc,
               const float* __restrict__ Wp2, const float* __restrict__ bp2,
               float* __restrict__ out)
{
  __shared__ float sA[64*260];   // ea1
  __shared__ float sH[64*260];   // h0 -> h1
  __shared__ float sB[16*256];   // B staging (split in half for dual-B GEMM)
  __shared__ int   sSrc[64], sDst[64];
  const int tid = threadIdx.x;
  const long e0 = (long)blockIdx.x * 64;
  const int* src = ei;
  const int* dst = ei + N_EDGES;
  const int ty = tid >> 5, tx = tid & 31;   // rows ty*4+r, cols tx+32*c

  if constexpr (STORE) {
    if (tid < 64)       sSrc[tid]    = src[e0 + tid];
    else if (tid < 128) sDst[tid-64] = dst[e0 + tid - 64];
#pragma unroll
    for (int j = 0; j < 8; j++) {
      int i = tid + 512*j, row = i >> 6, c4 = i & 63;
      *(float4*)&sA[row*260 + c4*4] = *(const float4*)&ea1g[(e0+row)*HD + c4*4];
    }
    __syncthreads();
  } else {
    // build h0 -> sH
    {
      const int el = tid >> 3, q = tid & 7;
      const long e = e0 + el;
      const int s = src[e], d = dst[e];
      if (q == 0) { sSrc[el] = s; sDst[el] = d; }
      float eav[6];
#pragma unroll
      for (int k = 0; k < 6; k++) eav[k] = eattr[e*6 + k];
      const float* ps = Pxs + (long)s*HD;
      const float* pd = Pxd + (long)d*HD;
      float* sh = sH + el*260;
#pragma unroll
      for (int t = 0; t < 8; t++) {
        const int j = t*32 + q*4;
        float4 a = *(const float4*)(ps + j);
        float4 b = *(const float4*)(pd + j);
        float4 bb = *(const float4*)(b0 + j);
        float vx = a.x + b.x + bb.x;
        float vy = a.y + b.y + bb.y;
        float vz = a.z + b.z + bb.z;
        float vw = a.w + b.w + bb.w;
#pragma unroll
        for (int k = 0; k < 6; k++) {
          float4 w = *(const float4*)(W6 + k*HD + j);
          vx += eav[k]*w.x; vy += eav[k]*w.y;
          vz += eav[k]*w.z; vw += eav[k]*w.w;
        }
        float4 o;
        o.x = fmaxf(vx, 0.f); o.y = fmaxf(vy, 0.f);
        o.z = fmaxf(vz, 0.f); o.w = fmaxf(vw, 0.f);
        *(float4*)(sh + j) = o;
      }
    }
    __syncthreads();

    // GEMM0: ea1 = h0 @ We0b + be0b -> sA   (KC=16)
    float acc[4][8];
#pragma unroll
    for (int r = 0; r < 4; r++)
#pragma unroll
      for (int c = 0; c < 8; c++) acc[r][c] = 0.f;
    for (int kb = 0; kb < HD; kb += 16) {
#pragma unroll
      for (int j = 0; j < 2; j++) {
        int i = tid + 512*j, row = i >> 6, c4 = i & 63;
        *(float4*)&sB[row*HD + c4*4] = *(const float4*)&We0b[(long)(kb+row)*HD + c4*4];
      }
      __syncthreads();
#pragma unroll 4
      for (int kk = 0; kk < 16; kk++) {
        float a0 = sH[(ty*4+0)*260 + kb+kk];
        float a1 = sH[(ty*4+1)*260 + kb+kk];
        float a2 = sH[(ty*4+2)*260 + kb+kk];
        float a3 = sH[(ty*4+3)*260 + kb+kk];
#pragma unroll
        for (int c = 0; c < 8; c++) {
          float b = sB[kk*HD + tx + 32*c];
          acc[0][c] += a0*b; acc[1][c] += a1*b;
          acc[2][c] += a2*b; acc[3][c] += a3*b;
        }
      }
      __syncthreads();
    }
    float bv[8];
#pragma unroll
    for (int c = 0; c < 8; c++) bv[c] = be0b[tx + 32*c];
#pragma unroll
    for (int r = 0; r < 4; r++)
#pragma unroll
      for (int c = 0; c < 8; c++)
        sA[(ty*4+r)*260 + tx + 32*c] = acc[r][c] + bv[c];
    __syncthreads();
  }

  // GEMM1 (dual-B): acc1 = ea1@WeE, accT = ea1@Wp1   (KC=8)
  float acc1[4][8], accT[4][8];
#pragma unroll
  for (int r = 0; r < 4; r++)
#pragma unroll
    for (int c = 0; c < 8; c++) { acc1[r][c] = 0.f; accT[r][c] = 0.f; }
  float* sB1 = sB;
  float* sB2 = sB + 8*256;
  for (int kb = 0; kb < HD; kb += 8) {
    { int row = tid >> 6, c4 = tid & 63;
      *(float4*)&sB1[row*HD + c4*4] = *(const float4*)&WeE[(long)(kb+row)*HD + c4*4];
      *(float4*)&sB2[row*HD + c4*4] = *(const float4*)&Wp1[(long)(kb+row)*HD + c4*4]; }
    __syncthreads();
#pragma unroll
    for (int kk = 0; kk < 8; kk++) {
      float a[4];
#pragma unroll
      for (int r = 0; r < 4; r++) a[r] = sA[(ty*4+r)*260 + kb+kk];
#pragma unroll
      for (int c = 0; c < 8; c++) {
        float b1v = sB1[kk*HD + tx + 32*c];
        float b2v = sB2[kk*HD + tx + 32*c];
#pragma unroll
        for (int r = 0; r < 4; r++) {
          acc1[r][c] += a[r]*b1v;
          accT[r][c] += a[r]*b2v;
        }
      }
    }
    __syncthreads();
  }

  // epilogue1: h1 = relu(acc1 + P1s[s] + P1d[d] + be1a) -> sH
  {
    float bv[8];
#pragma unroll
    for (int c = 0; c < 8; c++) bv[c] = be1a[tx + 32*c];
#pragma unroll
    for (int r = 0; r < 4; r++) {
      const int el = ty*4 + r;
      const int s = sSrc[el], d = sDst[el];
#pragma unroll
      for (int c = 0; c < 8; c++) {
        const int col = tx + 32*c;
        float v = acc1[r][c] + P1s[(long)s*HD + col] + P1d[(long)d*HD + col] + bv[c];
        sH[el*260 + col] = fmaxf(v, 0.f);
      }
    }
  }
  __syncthreads();

  // GEMM2: accZ = h1 @ Wc   (KC=16)
  float accZ[4][8];
#pragma unroll
  for (int r = 0; r < 4; r++)
#pragma unroll
    for (int c = 0; c < 8; c++) accZ[r][c] = 0.f;
  for (int kb = 0; kb < HD; kb += 16) {
#pragma unroll
    for (int j = 0; j < 2; j++) {
      int i = tid + 512*j, row = i >> 6, c4 = i & 63;
      *(float4*)&sB[row*HD + c4*4] = *(const float4*)&Wc[(long)(kb+row)*HD + c4*4];
    }
    __syncthreads();
#pragma unroll 4
    for (int kk = 0; kk < 16; kk++) {
      float a0 = sH[(ty*4+0)*260 + kb+kk];
      float a1 = sH[(ty*4+1)*260 + kb+kk];
      float a2 = sH[(ty*4+2)*260 + kb+kk];
      float a3 = sH[(ty*4+3)*260 + kb+kk];
#pragma unroll
      for (int c = 0; c < 8; c++) {
        float b = sB[kk*HD + tx + 32*c];
        accZ[0][c] += a0*b; accZ[1][c] += a1*b;
        accZ[2][c] += a2*b; accZ[3][c] += a3*b;
      }
    }
    __syncthreads();
  }

  // final: z = accZ + accT + bc; h2 = leaky_relu(z); p[r] = sum_col h2*Wp2
  float p[4] = {0.f, 0.f, 0.f, 0.f};
#pragma unroll
  for (int c = 0; c < 8; c++) {
    const int col = tx + 32*c;
    const float w   = Wp2[col];
    const float bcv = bc[col];
#pragma unroll
    for (int r = 0; r < 4; r++) {
      float z = accZ[r][c] + accT[r][c] + bcv;
      z = z > 0.f ? z : 0.01f*z;
      p[r] += z*w;
    }
  }
#pragma unroll
  for (int r = 0; r < 4; r++) {
    p[r] += __shfl_xor(p[r], 1);
    p[r] += __shfl_xor(p[r], 2);
    p[r] += __shfl_xor(p[r], 4);
    p[r] += __shfl_xor(p[r], 8);
    p[r] += __shfl_xor(p[r], 16);
  }
  if (tx == 0) {
    const float b2 = bp2[0];
#pragma unroll
    for (int r = 0; r < 4; r++) out[e0 + ty*4 + r] = p[r] + b2;
  }
}

// ---------------------------------------------------------------------------
extern "C" void kernel_launch(void* const* d_in, const int* in_sizes, int n_in,
                              void* d_out, int out_size, void* d_ws, size_t ws_size,
                              hipStream_t stream)
{
  const float* x     = (const float*)d_in[0];
  const int*   ei    = (const int*)d_in[1];
  const float* eattr = (const float*)d_in[2];
  const float* We0a  = (const float*)d_in[3];
  const float* be0a  = (const float*)d_in[4];
  const float* We0b  = (const float*)d_in[5];
  const float* be0b  = (const float*)d_in[6];
  const float* Wn0a  = (const float*)d_in[7];
  const float* bn0a  = (const float*)d_in[8];
  const float* Wn0b  = (const float*)d_in[9];
  const float* bn0b  = (const float*)d_in[10];
  const float* We1a  = (const float*)d_in[11];
  const float* be1a  = (const float*)d_in[12];
  const float* We1b  = (const float*)d_in[13];
  const float* be1b  = (const float*)d_in[14];
  // d_in[15..18] = Wn1a,bn1a,Wn1b,bn1b -> dead (x2 never reaches the output)
  const float* Wp1   = (const float*)d_in[19];
  const float* bp1   = (const float*)d_in[20];
  const float* Wp2   = (const float*)d_in[21];
  const float* bp2   = (const float*)d_in[22];
  float* out = (float*)d_out;
  float* ws  = (float*)d_ws;

  float* P_s  = ws;
  float* P_d  = ws + OFF_PD;
  float* bufA = ws + OFF_BA;
  float* bufB = ws + OFF_BB;
  float* bufC = ws + OFF_BC;
  float* deg  = ws + OFF_DEG;
  float* WcB  = ws + OFF_WC;
  float* bcB  = ws + OFF_BCV;
  float* ea1  = ws + OFF_EA1;

  const bool store = (ws_size >= NEED_STORE_BYTES);

  const float* W6  = We0a + 1024*HD;   // edge_attr rows of We0a
  const float* WeE = We1a + 512*HD;    // ea1 rows of We1a

  // zero agg + deg (contiguous)
  hipMemsetAsync(bufC, 0, (2560000 + 10000)*sizeof(float), stream);

  const int ngrid = (N_NODES + 63)/64;   // 157
  const int egrid = N_EDGES/64;          // 5000

  // Pxs / Pxd
  node_gemm<<<ngrid,256,0,stream>>>(x,512, nullptr,0,nullptr, We0a,        nullptr, P_s, N_NODES, 0);
  node_gemm<<<ngrid,256,0,stream>>>(x,512, nullptr,0,nullptr, We0a+512*HD, nullptr, P_d, N_NODES, 0);

  // Wc = We1b@Wp1 ; bc = be1b@Wp1 + bp1
  node_gemm<<<4,256,0,stream>>>(We1b,256, nullptr,0,nullptr, Wp1, nullptr, WcB, 256, 0);
  bc_k<<<1,256,0,stream>>>(be1b, Wp1, bp1, bcB);

  // conv_in edge stage: (ea1), agg, deg
  if (store)
    edge_conv_in<true ><<<egrid,512,0,stream>>>(ei, eattr, P_s, P_d, W6, be0a,
                                                We0b, be0b, ea1, bufC, deg);
  else
    edge_conv_in<false><<<egrid,512,0,stream>>>(ei, eattr, P_s, P_d, W6, be0a,
                                                We0b, be0b, nullptr, bufC, deg);

  rdeg_k<<<(N_NODES+255)/256,256,0,stream>>>(deg);

  // t1 = relu(x@Wn0a[0:512] + (agg*rdeg)@Wn0a[512:768] + bn0a)
  node_gemm<<<ngrid,256,0,stream>>>(x,512, bufC,256, deg, Wn0a, bn0a, bufA, N_NODES, 1);
  // x1 = t1@Wn0b + bn0b
  node_gemm<<<ngrid,256,0,stream>>>(bufA,256, nullptr,0,nullptr, Wn0b, bn0b, bufB, N_NODES, 0);
  // P1s = x1@We1a[0:256] ; P1d = x1@We1a[256:512]
  node_gemm<<<ngrid,256,0,stream>>>(bufB,256, nullptr,0,nullptr, We1a,        nullptr, bufA, N_NODES, 0);
  node_gemm<<<ngrid,256,0,stream>>>(bufB,256, nullptr,0,nullptr, We1a+256*HD, nullptr, bufC, N_NODES, 0);

  // fused conv[0] edge MLP + predictor
  if (store)
    edge_pred<true ><<<egrid,512,0,stream>>>(ei, ea1, eattr, P_s, P_d, W6, be0a,
        We0b, be0b, bufA, bufC, WeE, be1a, Wp1, WcB, bcB, Wp2, bp2, out);
  else
    edge_pred<false><<<egrid,512,0,stream>>>(ei, nullptr, eattr, P_s, P_d, W6, be0a,
        We0b, be0b, bufA, bufC, WeE, be1a, Wp1, WcB, bcB, Wp2, bp2, out);
}

// Round 3
// 2468.334 us; speedup vs baseline: 2.1297x; 2.1297x over previous
//
#include <hip/hip_runtime.h>

#define N_NODES 10000
#define N_EDGES 320000
#define HD      256

typedef __attribute__((ext_vector_type(8))) short bf16x8;
typedef __attribute__((ext_vector_type(4))) float f32x4;
#define MFMA16 __builtin_amdgcn_mfma_f32_16x16x32_bf16

// ---------------------------------------------------------------------------
// ws layout (floats), total 12,875,792 fl = 51.5 MB (== proven round-2 bound)
//   P_s   @ 0           [N,256]  x@We0a[0:512]     (live to end)
//   P_d   @ 2,560,000   [N,256]  x@We0a[512:1024]  (live to end)
//   bufA  @ 5,120,000   [N,256]  t1 -> P1s
//   bufB  @ 7,680,000   [N,256]  x1 -> prep area (WeE/Wp1/Wc splits, Wc fp32)
//   bufC  @ 10,240,000  [N,256]  agg -> P1d
//   deg   @ 12,800,000  [N]
//   bc    @ 12,810,000  [256]
//   pWe0b @ 12,810,256  [65,536 fl as 2x65,536 bf16 H|L]
// ---------------------------------------------------------------------------
#define OFF_PD    2560000
#define OFF_BA    5120000
#define OFF_BB    7680000
#define OFF_BC    10240000
#define OFF_DEG   12800000
#define OFF_BCV   12810000
#define OFF_PWE0B 12810256
#define OFF_PWEE  (7680000 + 2097152)   // 9,777,152
#define OFF_PWP1  (OFF_PWEE + 65536)
#define OFF_PWC   (OFF_PWP1 + 65536)
#define OFF_WCF   (OFF_PWC  + 65536)    // Wc fp32 [256,256]

__device__ __forceinline__ ushort f2bf(float x) {
  union { float f; unsigned u; } c; c.f = x;
  unsigned r = (c.u + 0x7FFFu + ((c.u >> 16) & 1u)) >> 16;
  return (ushort)r;
}
__device__ __forceinline__ float bf2f(ushort h) {
  union { float f; unsigned u; } c; c.u = ((unsigned)h) << 16; return c.f;
}

// ---------------------------------------------------------------------------
// prep_split: W[256][256] fp32 -> fragment-linear split-bf16 H|L.
// Frag layout (16x16x32 MFMA, B operand): H[((s*16+cf)*64+lane)*8+j] =
//   bf16(W[k][n]), k = s*32 + (lane>>4)*8 + j, n = cf*16 + (lane&15).
// ---------------------------------------------------------------------------
__global__ __launch_bounds__(256)
void prep_split(const float* __restrict__ W, ushort* __restrict__ H,
                ushort* __restrict__ L)
{
  int slot = blockIdx.x * 256 + threadIdx.x;      // 8192 slots
  int s    = slot >> 10;
  int rem  = slot & 1023;
  int cf   = rem >> 6;
  int lane = rem & 63;
  int k0 = s * 32 + ((lane >> 4) << 3);
  int n  = cf * 16 + (lane & 15);
#pragma unroll
  for (int j = 0; j < 8; ++j) {
    float v = W[(k0 + j) * HD + n];
    ushort hi = f2bf(v);
    H[slot * 8 + j] = hi;
    L[slot * 8 + j] = f2bf(v - bf2f(hi));
  }
}

// ---------------------------------------------------------------------------
// node GEMM (fp32 VALU, unchanged from round 2 — correct & small share)
// ---------------------------------------------------------------------------
__global__ __launch_bounds__(256)
void node_gemm(const float* __restrict__ A1, int K1,
               const float* __restrict__ A2, int K2,
               const float* __restrict__ scale,
               const float* __restrict__ W,
               const float* __restrict__ bias,
               float* __restrict__ C, int M, int act)
{
  __shared__ float sA[64 * 36];
  __shared__ float sB[32 * 256];
  __shared__ float sBias[256];
  const int tid = threadIdx.x;
  const int r0  = blockIdx.x * 64;
  if (bias) sBias[tid] = bias[tid];
  const int ty = tid >> 4, tx = tid & 15;

  float acc[4][16];
#pragma unroll
  for (int r = 0; r < 4; r++)
#pragma unroll
    for (int c = 0; c < 16; c++) acc[r][c] = 0.f;

  const int K = K1 + K2;
  const int arow = tid >> 2;
  const int aks  = (tid & 3) * 8;
  const int gr_a = r0 + arow;

  for (int kb = 0; kb < K; kb += 32) {
    const float* Ap; int lda, koff; float sc = 1.0f;
    if (kb < K1) { Ap = A1; lda = K1; koff = kb; }
    else { Ap = A2; lda = K2; koff = kb - K1;
           if (scale) sc = scale[gr_a < M ? gr_a : M - 1]; }
#pragma unroll
    for (int j = 0; j < 8; j += 4) {
      float4 v;
      if (gr_a < M) v = *(const float4*)&Ap[(long)gr_a * lda + koff + aks + j];
      else { v.x = v.y = v.z = v.w = 0.f; }
      v.x *= sc; v.y *= sc; v.z *= sc; v.w *= sc;
      *(float4*)&sA[arow * 36 + aks + j] = v;
    }
#pragma unroll
    for (int j = 0; j < 8; j++) {
      int i = tid + 256 * j, row = i >> 6, c4 = i & 63;
      *(float4*)&sB[row * HD + c4 * 4] = *(const float4*)&W[(long)(kb + row) * HD + c4 * 4];
    }
    __syncthreads();
#pragma unroll 4
    for (int kk = 0; kk < 32; kk++) {
      float a0 = sA[(ty * 4 + 0) * 36 + kk];
      float a1 = sA[(ty * 4 + 1) * 36 + kk];
      float a2 = sA[(ty * 4 + 2) * 36 + kk];
      float a3 = sA[(ty * 4 + 3) * 36 + kk];
#pragma unroll
      for (int c = 0; c < 16; c++) {
        float b = sB[kk * HD + tx + 16 * c];
        acc[0][c] += a0 * b; acc[1][c] += a1 * b;
        acc[2][c] += a2 * b; acc[3][c] += a3 * b;
      }
    }
    __syncthreads();
  }

#pragma unroll
  for (int r = 0; r < 4; r++) {
    int gr = r0 + ty * 4 + r;
    if (gr >= M) continue;
#pragma unroll
    for (int c = 0; c < 16; c++) {
      int col = tx + 16 * c;
      float v = acc[r][c];
      if (bias) v += sBias[col];
      if (act)  v = fmaxf(v, 0.f);
      C[(long)gr * HD + col] = v;
    }
  }
}

__global__ __launch_bounds__(256)
void bc_k(const float* __restrict__ be1b, const float* __restrict__ Wp1,
          const float* __restrict__ bp1, float* __restrict__ bc)
{
  const int j = threadIdx.x;
  float s = bp1[j];
  for (int k = 0; k < HD; k++) s += be1b[k] * Wp1[k * HD + j];
  bc[j] = s;
}

__global__ void rdeg_k(float* __restrict__ deg)
{
  int i = blockIdx.x * blockDim.x + threadIdx.x;
  if (i < N_NODES) deg[i] = 1.0f / fmaxf(deg[i], 1.0f);
}

// ---------------------------------------------------------------------------
// Shared device helpers for the edge kernels (1024 threads, 64 edges/tile).
// A tile in LDS: bf16 [64][256] hi+lo, row stride 512B, XOR swizzle
// byte ^= (row&7)<<4  (spreads the 512B row stride across banks; 2-way max).
// ---------------------------------------------------------------------------
__device__ __forceinline__ void build_h0(
    int tid, const float* __restrict__ Ps, const float* __restrict__ Pd,
    const float* sEA, const float* sW6, const float* sB0,
    const int* sSrc, const int* sDst, ushort* Ah, ushort* Al)
{
  const int el = tid >> 4, q = tid & 15;
  const int sv = sSrc[el], dv = sDst[el];
  float eav[6];
#pragma unroll
  for (int k = 0; k < 6; ++k) eav[k] = sEA[el * 6 + k];
  const float* ps = Ps + (long)sv * HD + q * 16;
  const float* pd = Pd + (long)dv * HD + q * 16;
  const int sw = (el & 7) << 4;
  char* ahB = (char*)Ah + el * 512;
  char* alB = (char*)Al + el * 512;
#pragma unroll
  for (int jj = 0; jj < 4; ++jj) {
    float4 a  = *(const float4*)(ps + jj * 4);
    float4 b  = *(const float4*)(pd + jj * 4);
    float4 bb = *(const float4*)(sB0 + q * 16 + jj * 4);
    float vx = a.x + b.x + bb.x;
    float vy = a.y + b.y + bb.y;
    float vz = a.z + b.z + bb.z;
    float vw = a.w + b.w + bb.w;
#pragma unroll
    for (int k = 0; k < 6; ++k) {
      float4 w = *(const float4*)(sW6 + k * HD + q * 16 + jj * 4);
      vx += eav[k] * w.x; vy += eav[k] * w.y;
      vz += eav[k] * w.z; vw += eav[k] * w.w;
    }
    vx = fmaxf(vx, 0.f); vy = fmaxf(vy, 0.f);
    vz = fmaxf(vz, 0.f); vw = fmaxf(vw, 0.f);
    ushort4 hh, ll;
    hh.x = f2bf(vx); hh.y = f2bf(vy); hh.z = f2bf(vz); hh.w = f2bf(vw);
    ll.x = f2bf(vx - bf2f(hh.x)); ll.y = f2bf(vy - bf2f(hh.y));
    ll.z = f2bf(vz - bf2f(hh.z)); ll.w = f2bf(vw - bf2f(hh.w));
    const int off = (q * 32 + jj * 8) ^ sw;
    *(ushort4*)(ahB + off) = hh;
    *(ushort4*)(alB + off) = ll;
  }
}

__device__ __forceinline__ void write_split(ushort* Ah, ushort* Al,
                                            int row, int col, float v)
{
  const int off = row * 512 + ((col * 2) ^ ((row & 7) << 4));
  ushort hi = f2bf(v);
  *(ushort*)((char*)Ah + off) = hi;
  *(ushort*)((char*)Al + off) = f2bf(v - bf2f(hi));
}

// single-matrix bf16x3 GEMM pass: acc[4cf] += A(64x256) @ W(256x256) slice
__device__ __forceinline__ void gemm_bf3_1(
    const ushort* __restrict__ pH, const ushort* __restrict__ pL,
    ushort* Bs, const ushort* Ah, const ushort* Al,
    int tid, int lane, int wc, int arow, f32x4 acc[4])
{
  const int asw = (arow & 7) << 4;
  for (int s = 0; s < 8; ++s) {
    // stage 32KB slab (H 16KB | L 16KB) through regs: 2048 x 16B pieces
#pragma unroll
    for (int i = 0; i < 2; ++i) {
      int idx16 = tid + (i << 10);
      int c = idx16 >> 6, w16 = idx16 & 63;
      const ushort* src = (c < 16 ? pH : pL) + s * 8192 + (c & 15) * 512 + w16 * 8;
      *(uint4*)(Bs + idx16 * 8) = *(const uint4*)src;
    }
    __syncthreads();
    const int aoff = arow * 512 + (((s << 6) + ((lane >> 4) << 4)) ^ asw);
    bf16x8 ah = *(const bf16x8*)((const char*)Ah + aoff);
    bf16x8 al = *(const bf16x8*)((const char*)Al + aoff);
#pragma unroll
    for (int cf = 0; cf < 4; ++cf) {
      const int cfg = wc * 4 + cf;
      bf16x8 bh = *(const bf16x8*)((const char*)Bs + cfg * 1024 + lane * 16);
      bf16x8 bl = *(const bf16x8*)((const char*)Bs + 16384 + cfg * 1024 + lane * 16);
      acc[cf] = MFMA16(ah, bh, acc[cf], 0, 0, 0);
      acc[cf] = MFMA16(ah, bl, acc[cf], 0, 0, 0);
      acc[cf] = MFMA16(al, bh, acc[cf], 0, 0, 0);
    }
    __syncthreads();
  }
}

// ---------------------------------------------------------------------------
// conv_in edge stage (MFMA): h0 -> ea1 = h0@We0b + be0b -> atomic agg/deg
// ---------------------------------------------------------------------------
__global__ __launch_bounds__(1024)
void edge_conv_in(const int* __restrict__ ei, const float* __restrict__ eattr,
                  const float* __restrict__ Ps, const float* __restrict__ Pd,
                  const float* __restrict__ W6, const float* __restrict__ b0,
                  const ushort* __restrict__ pW0H, const ushort* __restrict__ pW0L,
                  const float* __restrict__ be0b,
                  float* __restrict__ agg, float* __restrict__ deg)
{
  __shared__ ushort Ah[64 * 256];
  __shared__ ushort Al[64 * 256];
  __shared__ ushort Bs[16384];          // 32KB slab
  __shared__ float  sW6[6 * 256];
  __shared__ float  sEA[64 * 6];
  __shared__ float  sB0[256];
  __shared__ int    sSrc[64], sDst[64];
  const int tid = threadIdx.x;
  const long e0 = (long)blockIdx.x * 64;

  if (tid < 64) {
    int dv = ei[N_EDGES + e0 + tid];
    sDst[tid] = dv;
    atomicAdd(&deg[dv], 1.0f);
  } else if (tid < 128) {
    sSrc[tid - 64] = ei[e0 + tid - 64];
  }
  if (tid < 96)  *(float4*)&sEA[tid * 4] = *(const float4*)&eattr[e0 * 6 + tid * 4];
  if (tid < 384) *(float4*)&sW6[tid * 4] = *(const float4*)&W6[tid * 4];
  if (tid < 64)  *(float4*)&sB0[tid * 4] = *(const float4*)&b0[tid * 4];
  __syncthreads();

  build_h0(tid, Ps, Pd, sEA, sW6, sB0, sSrc, sDst, Ah, Al);
  __syncthreads();

  const int lane = tid & 63, wid = tid >> 6;
  const int wr = wid & 3, wc = wid >> 2;
  const int arow = wr * 16 + (lane & 15);

  f32x4 acc[4];
#pragma unroll
  for (int cf = 0; cf < 4; ++cf) acc[cf] = (f32x4){0.f, 0.f, 0.f, 0.f};
  gemm_bf3_1(pW0H, pW0L, Bs, Ah, Al, tid, lane, wc, arow, acc);

  const int rbase = wr * 16 + ((lane >> 4) << 2);
#pragma unroll
  for (int cf = 0; cf < 4; ++cf) {
    const int col = wc * 64 + cf * 16 + (lane & 15);
    const float bv = be0b[col];
#pragma unroll
    for (int r = 0; r < 4; ++r) {
      const int row = rbase + r;
      atomicAdd(&agg[(long)sDst[row] * HD + col], acc[cf][r] + bv);
    }
  }
}

// ---------------------------------------------------------------------------
// Fused conv[0] edge MLP + predictor (MFMA, recompute ea1):
//   h0  = relu(Ps[s]+Pd[d]+ea@W6+b0)         (fp32 VALU)
//   ea1 = h0@We0b + be0b                     (GEMM0)
//   h1  = relu(ea1@WeE + P1s[s]+P1d[d]+be1a) (GEMM1a)
//   t   = ea1@Wp1                            (GEMM1b, reg-resident)
//   z   = h1@Wc + t + bc                     (GEMM2; Wc=We1b@Wp1 folds residual)
//   out = leaky_relu(z)@Wp2 + bp2
// ---------------------------------------------------------------------------
__global__ __launch_bounds__(1024)
void edge_pred(const int* __restrict__ ei, const float* __restrict__ eattr,
               const float* __restrict__ Ps, const float* __restrict__ Pd,
               const float* __restrict__ W6, const float* __restrict__ b0,
               const ushort* __restrict__ pW0H, const ushort* __restrict__ pW0L,
               const float* __restrict__ be0b,
               const float* __restrict__ P1s, const float* __restrict__ P1d,
               const ushort* __restrict__ pWeE, const ushort* __restrict__ pWp1,
               const ushort* __restrict__ pWc,
               const float* __restrict__ be1a, const float* __restrict__ bc,
               const float* __restrict__ Wp2, const float* __restrict__ bp2,
               float* __restrict__ out)
{
  __shared__ ushort Ah[64 * 256];
  __shared__ ushort Al[64 * 256];
  __shared__ ushort Bs[32768];          // 64KB slab (dual GEMM1)
  __shared__ float  sW6[6 * 256];
  __shared__ float  sEA[64 * 6];
  __shared__ float  sB0[256];
  __shared__ float  sOut[64];
  __shared__ int    sSrc[64], sDst[64];
  const int tid = threadIdx.x;
  const long e0 = (long)blockIdx.x * 64;

  if (tid < 64) {
    sDst[tid] = ei[N_EDGES + e0 + tid];
    sOut[tid] = bp2[0];
  } else if (tid < 128) {
    sSrc[tid - 64] = ei[e0 + tid - 64];
  }
  if (tid < 96)  *(float4*)&sEA[tid * 4] = *(const float4*)&eattr[e0 * 6 + tid * 4];
  if (tid < 384) *(float4*)&sW6[tid * 4] = *(const float4*)&W6[tid * 4];
  if (tid < 64)  *(float4*)&sB0[tid * 4] = *(const float4*)&b0[tid * 4];
  __syncthreads();

  build_h0(tid, Ps, Pd, sEA, sW6, sB0, sSrc, sDst, Ah, Al);
  __syncthreads();

  const int lane = tid & 63, wid = tid >> 6;
  const int wr = wid & 3, wc = wid >> 2;
  const int arow = wr * 16 + (lane & 15);
  const int asw  = (arow & 7) << 4;
  const int rbase = wr * 16 + ((lane >> 4) << 2);

  // ---- GEMM0: ea1 = h0@We0b + be0b -> back into Ah/Al ----
  {
    f32x4 acc[4];
#pragma unroll
    for (int cf = 0; cf < 4; ++cf) acc[cf] = (f32x4){0.f, 0.f, 0.f, 0.f};
    gemm_bf3_1(pW0H, pW0L, Bs, Ah, Al, tid, lane, wc, arow, acc);
#pragma unroll
    for (int cf = 0; cf < 4; ++cf) {
      const int col = wc * 64 + cf * 16 + (lane & 15);
      const float bv = be0b[col];
#pragma unroll
      for (int r = 0; r < 4; ++r)
        write_split(Ah, Al, rbase + r, col, acc[cf][r] + bv);
    }
  }
  // (no barrier needed: GEMM1's stage+sync orders these writes before reads)

  // ---- GEMM1 dual: acc1 = ea1@WeE, accT = ea1@Wp1 ----
  f32x4 acc1[4], accT[4];
#pragma unroll
  for (int cf = 0; cf < 4; ++cf) {
    acc1[cf] = (f32x4){0.f, 0.f, 0.f, 0.f};
    accT[cf] = (f32x4){0.f, 0.f, 0.f, 0.f};
  }
  for (int s = 0; s < 8; ++s) {
    // stage 64KB: [WeE_H|WeE_L|Wp1_H|Wp1_L] 16KB each
#pragma unroll
    for (int i = 0; i < 4; ++i) {
      int idx16 = tid + (i << 10);
      int c = idx16 >> 6, w16 = idx16 & 63;
      const ushort* base = (c < 32 ? pWeE : pWp1) + ((c >> 4) & 1) * 65536;
      const ushort* src = base + s * 8192 + (c & 15) * 512 + w16 * 8;
      *(uint4*)(Bs + idx16 * 8) = *(const uint4*)src;
    }
    __syncthreads();
    const int aoff = arow * 512 + (((s << 6) + ((lane >> 4) << 4)) ^ asw);
    bf16x8 ah = *(const bf16x8*)((const char*)Ah + aoff);
    bf16x8 al = *(const bf16x8*)((const char*)Al + aoff);
#pragma unroll
    for (int cf = 0; cf < 4; ++cf) {
      const int cfg = wc * 4 + cf;
      bf16x8 b1h = *(const bf16x8*)((const char*)Bs + cfg * 1024 + lane * 16);
      bf16x8 b1l = *(const bf16x8*)((const char*)Bs + 16384 + cfg * 1024 + lane * 16);
      bf16x8 b2h = *(const bf16x8*)((const char*)Bs + 32768 + cfg * 1024 + lane * 16);
      bf16x8 b2l = *(const bf16x8*)((const char*)Bs + 49152 + cfg * 1024 + lane * 16);
      acc1[cf] = MFMA16(ah, b1h, acc1[cf], 0, 0, 0);
      acc1[cf] = MFMA16(ah, b1l, acc1[cf], 0, 0, 0);
      acc1[cf] = MFMA16(al, b1h, acc1[cf], 0, 0, 0);
      accT[cf] = MFMA16(ah, b2h, accT[cf], 0, 0, 0);
      accT[cf] = MFMA16(ah, b2l, accT[cf], 0, 0, 0);
      accT[cf] = MFMA16(al, b2h, accT[cf], 0, 0, 0);
    }
    __syncthreads();
  }

  // ---- epilogue1: h1 = relu(acc1 + P1s[s]+P1d[d]+be1a) -> Ah/Al ----
#pragma unroll
  for (int cf = 0; cf < 4; ++cf) {
    const int col = wc * 64 + cf * 16 + (lane & 15);
    const float bv = be1a[col];
#pragma unroll
    for (int r = 0; r < 4; ++r) {
      const int row = rbase + r;
      float v = acc1[cf][r] + P1s[(long)sSrc[row] * HD + col]
                            + P1d[(long)sDst[row] * HD + col] + bv;
      write_split(Ah, Al, row, col, fmaxf(v, 0.f));
    }
  }

  // ---- GEMM2: accZ = h1@Wc ; z = accZ + accT + bc ----
  f32x4 accZ[4];
#pragma unroll
  for (int cf = 0; cf < 4; ++cf) accZ[cf] = (f32x4){0.f, 0.f, 0.f, 0.f};
  gemm_bf3_1(pWc, pWc + 65536, Bs, Ah, Al, tid, lane, wc, arow, accZ);

  float p[4] = {0.f, 0.f, 0.f, 0.f};
#pragma unroll
  for (int cf = 0; cf < 4; ++cf) {
    const int col = wc * 64 + cf * 16 + (lane & 15);
    const float w   = Wp2[col];
    const float bcv = bc[col];
#pragma unroll
    for (int r = 0; r < 4; ++r) {
      float z = accZ[cf][r] + accT[cf][r] + bcv;
      z = z > 0.f ? z : 0.01f * z;
      p[r] += z * w;
    }
  }
#pragma unroll
  for (int r = 0; r < 4; ++r) {
    p[r] += __shfl_xor(p[r], 1);
    p[r] += __shfl_xor(p[r], 2);
    p[r] += __shfl_xor(p[r], 4);
    p[r] += __shfl_xor(p[r], 8);
  }
  if ((lane & 15) == 0) {
#pragma unroll
    for (int r = 0; r < 4; ++r) atomicAdd(&sOut[rbase + r], p[r]);
  }
  __syncthreads();
  if (tid < 64) out[e0 + tid] = sOut[tid];
}

// ---------------------------------------------------------------------------
extern "C" void kernel_launch(void* const* d_in, const int* in_sizes, int n_in,
                              void* d_out, int out_size, void* d_ws, size_t ws_size,
                              hipStream_t stream)
{
  const float* x     = (const float*)d_in[0];
  const int*   ei    = (const int*)d_in[1];
  const float* eattr = (const float*)d_in[2];
  const float* We0a  = (const float*)d_in[3];
  const float* be0a  = (const float*)d_in[4];
  const float* We0b  = (const float*)d_in[5];
  const float* be0b  = (const float*)d_in[6];
  const float* Wn0a  = (const float*)d_in[7];
  const float* bn0a  = (const float*)d_in[8];
  const float* Wn0b  = (const float*)d_in[9];
  const float* bn0b  = (const float*)d_in[10];
  const float* We1a  = (const float*)d_in[11];
  const float* be1a  = (const float*)d_in[12];
  const float* We1b  = (const float*)d_in[13];
  const float* be1b  = (const float*)d_in[14];
  // d_in[15..18] dead (conv[0] node MLP never reaches the output)
  const float* Wp1   = (const float*)d_in[19];
  const float* bp1   = (const float*)d_in[20];
  const float* Wp2   = (const float*)d_in[21];
  const float* bp2   = (const float*)d_in[22];
  float* out = (float*)d_out;
  float* ws  = (float*)d_ws;

  float* P_s  = ws;
  float* P_d  = ws + OFF_PD;
  float* bufA = ws + OFF_BA;
  float* bufB = ws + OFF_BB;
  float* bufC = ws + OFF_BC;
  float* deg  = ws + OFF_DEG;
  float* bcB  = ws + OFF_BCV;
  ushort* pW0  = (ushort*)(ws + OFF_PWE0B);   // H | L (65536 ushorts each)
  ushort* pWeE = (ushort*)(ws + OFF_PWEE);
  ushort* pWp1 = (ushort*)(ws + OFF_PWP1);
  ushort* pWc  = (ushort*)(ws + OFF_PWC);
  float*  WcF  = ws + OFF_WCF;

  const float* W6  = We0a + 1024 * HD;   // edge_attr rows of We0a
  const float* WeE = We1a + 512 * HD;    // ea1 rows of We1a

  // zero agg + deg (contiguous)
  hipMemsetAsync(bufC, 0, (2560000 + 10000) * sizeof(float), stream);

  const int ngrid = (N_NODES + 63) / 64;   // 157
  const int egrid = N_EDGES / 64;          // 5000

  // Pxs / Pxd, We0b split, bc
  node_gemm<<<ngrid, 256, 0, stream>>>(x, 512, nullptr, 0, nullptr, We0a,            nullptr, P_s, N_NODES, 0);
  node_gemm<<<ngrid, 256, 0, stream>>>(x, 512, nullptr, 0, nullptr, We0a + 512 * HD, nullptr, P_d, N_NODES, 0);
  prep_split<<<32, 256, 0, stream>>>(We0b, pW0, pW0 + 65536);
  bc_k<<<1, 256, 0, stream>>>(be1b, Wp1, bp1, bcB);

  // conv_in edge stage -> agg, deg
  edge_conv_in<<<egrid, 1024, 0, stream>>>(ei, eattr, P_s, P_d, W6, be0a,
                                           pW0, pW0 + 65536, be0b, bufC, deg);
  rdeg_k<<<(N_NODES + 255) / 256, 256, 0, stream>>>(deg);

  // node pipeline
  node_gemm<<<ngrid, 256, 0, stream>>>(x, 512, bufC, 256, deg, Wn0a, bn0a, bufA, N_NODES, 1); // t1
  node_gemm<<<ngrid, 256, 0, stream>>>(bufA, 256, nullptr, 0, nullptr, Wn0b, bn0b, bufB, N_NODES, 0); // x1
  node_gemm<<<ngrid, 256, 0, stream>>>(bufB, 256, nullptr, 0, nullptr, We1a,            nullptr, bufA, N_NODES, 0); // P1s
  node_gemm<<<ngrid, 256, 0, stream>>>(bufB, 256, nullptr, 0, nullptr, We1a + 256 * HD, nullptr, bufC, N_NODES, 0); // P1d

  // Wc = We1b@Wp1 (fp32) then split WeE/Wp1/Wc (bufB is dead now)
  node_gemm<<<4, 256, 0, stream>>>(We1b, 256, nullptr, 0, nullptr, Wp1, nullptr, WcF, 256, 0);
  prep_split<<<32, 256, 0, stream>>>(WeE, pWeE, pWeE + 65536);
  prep_split<<<32, 256, 0, stream>>>(Wp1, pWp1, pWp1 + 65536);
  prep_split<<<32, 256, 0, stream>>>(WcF, pWc,  pWc  + 65536);

  // fused conv[0] edge MLP + predictor
  edge_pred<<<egrid, 1024, 0, stream>>>(ei, eattr, P_s, P_d, W6, be0a,
      pW0, pW0 + 65536, be0b, bufA, bufC, pWeE, pWp1, pWc,
      be1a, bcB, Wp2, bp2, out);
}

// Round 5
// 2221.584 us; speedup vs baseline: 2.3662x; 1.1111x over previous
//
#include <hip/hip_runtime.h>

#define N_NODES 10000
#define N_EDGES 320000
#define HD      256

typedef __attribute__((ext_vector_type(8))) short bf16x8;
typedef __attribute__((ext_vector_type(4))) float f32x4;
#define MFMA16 __builtin_amdgcn_mfma_f32_16x16x32_bf16

// ---------------------------------------------------------------------------
// ws layout (floats), max offset 12,941,584 fl = 51.77 MB (proven in round 3)
//   P_s  @ 0           [N,256]
//   P_d  @ 2,560,000   [N,256]
//   bufA @ 5,120,000   t1 -> P1s
//   bufB @ 7,680,000   x1 -> (dead) -> WAf/WBf/WcF + pWA/pWB/pWc
//   bufC @ 10,240,000  agg -> P1d
//   deg  @ 12,800,000  [N]
//   bc   @ 12,810,000  [256]   (be1b+be0b)@Wp1 + bp1
//   bA   @ 12,810,256  [256]   be0b@WeE + be1a
//   pW0  @ 12,810,512  We0b split H|L (131,072 ushorts = 65,536 fl)
// ---------------------------------------------------------------------------
#define OFF_PD   2560000
#define OFF_BA   5120000
#define OFF_BB   7680000
#define OFF_BC   10240000
#define OFF_DEG  12800000
#define OFF_BCV  12810000
#define OFF_BAV  12810256
#define OFF_PW0  12810512

__device__ __forceinline__ ushort f2bf(float x) {
  union { float f; unsigned u; } c; c.f = x;
  unsigned r = (c.u + 0x7FFFu + ((c.u >> 16) & 1u)) >> 16;
  return (ushort)r;
}
__device__ __forceinline__ float bf2f(ushort h) {
  union { float f; unsigned u; } c; c.u = ((unsigned)h) << 16; return c.f;
}

// ---------------------------------------------------------------------------
// prep_split: W[256][256] fp32 -> fragment-linear split-bf16 H|L (validated r3)
// slot=(s*16+cfg)*64+lane holds j=0..7: W[s*32+(lane>>4)*8+j][cfg*16+(lane&15)]
// ---------------------------------------------------------------------------
__global__ __launch_bounds__(256)
void prep_split(const float* __restrict__ W, ushort* __restrict__ H,
                ushort* __restrict__ L)
{
  int slot = blockIdx.x * 256 + threadIdx.x;
  int s    = slot >> 10;
  int rem  = slot & 1023;
  int cf   = rem >> 6;
  int lane = rem & 63;
  int k0 = s * 32 + ((lane >> 4) << 3);
  int n  = cf * 16 + (lane & 15);
#pragma unroll
  for (int j = 0; j < 8; ++j) {
    float v = W[(k0 + j) * HD + n];
    ushort hi = f2bf(v);
    H[slot * 8 + j] = hi;
    L[slot * 8 + j] = f2bf(v - bf2f(hi));
  }
}

// ---------------------------------------------------------------------------
// node GEMM (fp32 VALU, unchanged — validated)
// ---------------------------------------------------------------------------
__global__ __launch_bounds__(256)
void node_gemm(const float* __restrict__ A1, int K1,
               const float* __restrict__ A2, int K2,
               const float* __restrict__ scale,
               const float* __restrict__ W,
               const float* __restrict__ bias,
               float* __restrict__ C, int M, int act)
{
  __shared__ float sA[64 * 36];
  __shared__ float sB[32 * 256];
  __shared__ float sBias[256];
  const int tid = threadIdx.x;
  const int r0  = blockIdx.x * 64;
  if (bias) sBias[tid] = bias[tid];
  const int ty = tid >> 4, tx = tid & 15;

  float acc[4][16];
#pragma unroll
  for (int r = 0; r < 4; r++)
#pragma unroll
    for (int c = 0; c < 16; c++) acc[r][c] = 0.f;

  const int K = K1 + K2;
  const int arow = tid >> 2;
  const int aks  = (tid & 3) * 8;
  const int gr_a = r0 + arow;

  for (int kb = 0; kb < K; kb += 32) {
    const float* Ap; int lda, koff; float sc = 1.0f;
    if (kb < K1) { Ap = A1; lda = K1; koff = kb; }
    else { Ap = A2; lda = K2; koff = kb - K1;
           if (scale) sc = scale[gr_a < M ? gr_a : M - 1]; }
#pragma unroll
    for (int j = 0; j < 8; j += 4) {
      float4 v;
      if (gr_a < M) v = *(const float4*)&Ap[(long)gr_a * lda + koff + aks + j];
      else { v.x = v.y = v.z = v.w = 0.f; }
      v.x *= sc; v.y *= sc; v.z *= sc; v.w *= sc;
      *(float4*)&sA[arow * 36 + aks + j] = v;
    }
#pragma unroll
    for (int j = 0; j < 8; j++) {
      int i = tid + 256 * j, row = i >> 6, c4 = i & 63;
      *(float4*)&sB[row * HD + c4 * 4] = *(const float4*)&W[(long)(kb + row) * HD + c4 * 4];
    }
    __syncthreads();
#pragma unroll 4
    for (int kk = 0; kk < 32; kk++) {
      float a0 = sA[(ty * 4 + 0) * 36 + kk];
      float a1 = sA[(ty * 4 + 1) * 36 + kk];
      float a2 = sA[(ty * 4 + 2) * 36 + kk];
      float a3 = sA[(ty * 4 + 3) * 36 + kk];
#pragma unroll
      for (int c = 0; c < 16; c++) {
        float b = sB[kk * HD + tx + 16 * c];
        acc[0][c] += a0 * b; acc[1][c] += a1 * b;
        acc[2][c] += a2 * b; acc[3][c] += a3 * b;
      }
    }
    __syncthreads();
  }

#pragma unroll
  for (int r = 0; r < 4; r++) {
    int gr = r0 + ty * 4 + r;
    if (gr >= M) continue;
#pragma unroll
    for (int c = 0; c < 16; c++) {
      int col = tx + 16 * c;
      float v = acc[r][c];
      if (bias) v += sBias[col];
      if (act)  v = fmaxf(v, 0.f);
      C[(long)gr * HD + col] = v;
    }
  }
}

// out[j] = base[j] + sum_k (v1[k] + v2?[k]) * W[k][j]
__global__ __launch_bounds__(256)
void bias_fold_k(const float* __restrict__ v1, const float* __restrict__ v2,
                 const float* __restrict__ W, const float* __restrict__ base,
                 float* __restrict__ out)
{
  const int j = threadIdx.x;
  float s = base[j];
  for (int k = 0; k < HD; k++) {
    float v = v1[k] + (v2 ? v2[k] : 0.f);
    s += v * W[k * HD + j];
  }
  out[j] = s;
}

__global__ void rdeg_k(float* __restrict__ deg)
{
  int i = blockIdx.x * blockDim.x + threadIdx.x;
  if (i < N_NODES) deg[i] = 1.0f / fmaxf(deg[i], 1.0f);
}

// ---------------------------------------------------------------------------
// build_h0 (512 threads, 64 edges): h0 = relu(Ps[s]+Pd[d]+ea@W6+b0) -> Ah/Al
// A tile LDS layout: bf16 [64][256] hi+lo, row stride 512B,
// byte_off ^= (row&7)<<4  (validated round 3)
// ---------------------------------------------------------------------------
__device__ __forceinline__ void build_h0(
    int tid, const float* __restrict__ Ps, const float* __restrict__ Pd,
    const float* sEA, const float* sW6, const float* sB0,
    const int* sSrc, const int* sDst, ushort* Ah, ushort* Al)
{
  const int el = tid >> 3, q = tid & 7;
  const int sv = sSrc[el], dv = sDst[el];
  float eav[6];
#pragma unroll
  for (int k = 0; k < 6; ++k) eav[k] = sEA[el * 6 + k];
  const float* ps = Ps + (long)sv * HD + q * 32;
  const float* pd = Pd + (long)dv * HD + q * 32;
  const int sw = (el & 7) << 4;
  char* ahB = (char*)Ah + el * 512;
  char* alB = (char*)Al + el * 512;
#pragma unroll
  for (int jj = 0; jj < 8; ++jj) {
    float4 a  = *(const float4*)(ps + jj * 4);
    float4 b  = *(const float4*)(pd + jj * 4);
    float4 bb = *(const float4*)(sB0 + q * 32 + jj * 4);
    float vx = a.x + b.x + bb.x;
    float vy = a.y + b.y + bb.y;
    float vz = a.z + b.z + bb.z;
    float vw = a.w + b.w + bb.w;
#pragma unroll
    for (int k = 0; k < 6; ++k) {
      float4 w = *(const float4*)(sW6 + k * HD + q * 32 + jj * 4);
      vx += eav[k] * w.x; vy += eav[k] * w.y;
      vz += eav[k] * w.z; vw += eav[k] * w.w;
    }
    vx = fmaxf(vx, 0.f); vy = fmaxf(vy, 0.f);
    vz = fmaxf(vz, 0.f); vw = fmaxf(vw, 0.f);
    ushort4 hh, ll;
    hh.x = f2bf(vx); hh.y = f2bf(vy); hh.z = f2bf(vz); hh.w = f2bf(vw);
    ll.x = f2bf(vx - bf2f(hh.x)); ll.y = f2bf(vy - bf2f(hh.y));
    ll.z = f2bf(vz - bf2f(hh.z)); ll.w = f2bf(vw - bf2f(hh.w));
    const int off = (q * 64 + jj * 8) ^ sw;
    *(ushort4*)(ahB + off) = hh;
    *(ushort4*)(alB + off) = ll;
  }
}

__device__ __forceinline__ void write_split(ushort* Ah, ushort* Al,
                                            int row, int col, float v)
{
  const int off = row * 512 + ((col * 2) ^ ((row & 7) << 4));
  ushort hi = f2bf(v);
  *(ushort*)((char*)Ah + off) = hi;
  *(ushort*)((char*)Al + off) = f2bf(v - bf2f(hi));
}

__device__ __forceinline__ void load_afrag(const ushort* Ah, const ushort* Al,
    int row, int s, int lane, bf16x8& ah, bf16x8& al)
{
  const int aoff = row * 512 + ((((s << 6) + ((lane >> 4) << 4))) ^ ((row & 7) << 4));
  ah = *(const bf16x8*)((const char*)Ah + aoff);
  al = *(const bf16x8*)((const char*)Al + aoff);
}

// ---------------------------------------------------------------------------
// conv_in edge stage: h0 -> ea1 = h0@We0b + be0b -> atomic agg/deg.
// 512 threads, 64 edges/block, B frags direct from global (no staging).
// ---------------------------------------------------------------------------
__global__ __launch_bounds__(512, 4)
void edge_conv_in(const int* __restrict__ ei, const float* __restrict__ eattr,
                  const float* __restrict__ Ps, const float* __restrict__ Pd,
                  const float* __restrict__ W6, const float* __restrict__ b0,
                  const ushort* __restrict__ pW0,
                  const float* __restrict__ be0b,
                  float* __restrict__ agg, float* __restrict__ deg)
{
  __shared__ ushort Ah[64 * 256];
  __shared__ ushort Al[64 * 256];
  __shared__ float  sW6[6 * 256];
  __shared__ float  sEA[64 * 6];
  __shared__ float  sB0[256];
  __shared__ int    sSrc[64], sDst[64];
  const int tid = threadIdx.x;
  const long e0 = (long)blockIdx.x * 64;

  if (tid < 64) {
    int dv = ei[N_EDGES + e0 + tid];
    sDst[tid] = dv;
    atomicAdd(&deg[dv], 1.0f);
  } else if (tid < 128) {
    sSrc[tid - 64] = ei[e0 + tid - 64];
  }
  if (tid < 96)  *(float4*)&sEA[tid * 4] = *(const float4*)&eattr[e0 * 6 + tid * 4];
  if (tid < 384) *(float4*)&sW6[tid * 4] = *(const float4*)&W6[tid * 4];
  if (tid < 64)  *(float4*)&sB0[tid * 4] = *(const float4*)&b0[tid * 4];
  __syncthreads();

  build_h0(tid, Ps, Pd, sEA, sW6, sB0, sSrc, sDst, Ah, Al);
  __syncthreads();

  const int lane = tid & 63, wid = tid >> 6;
  const int wc = wid & 3, wrg = wid >> 2;
  const bf16x8* pH = (const bf16x8*)pW0;
  const bf16x8* pL = (const bf16x8*)(pW0 + 65536);

  f32x4 acc[2][4];
#pragma unroll
  for (int rb = 0; rb < 2; ++rb)
#pragma unroll
    for (int cf = 0; cf < 4; ++cf) acc[rb][cf] = (f32x4){0.f, 0.f, 0.f, 0.f};

#pragma unroll 2
  for (int s = 0; s < 8; ++s) {
    bf16x8 ah[2], al[2];
#pragma unroll
    for (int rb = 0; rb < 2; ++rb)
      load_afrag(Ah, Al, (wrg * 2 + rb) * 16 + (lane & 15), s, lane, ah[rb], al[rb]);
#pragma unroll
    for (int cf = 0; cf < 4; ++cf) {
      const int slot = s * 1024 + (wc * 4 + cf) * 64 + lane;
      bf16x8 bh = pH[slot];
      bf16x8 bl = pL[slot];
#pragma unroll
      for (int rb = 0; rb < 2; ++rb) {
        acc[rb][cf] = MFMA16(al[rb], bh, acc[rb][cf], 0, 0, 0);
        acc[rb][cf] = MFMA16(ah[rb], bl, acc[rb][cf], 0, 0, 0);
        acc[rb][cf] = MFMA16(ah[rb], bh, acc[rb][cf], 0, 0, 0);
      }
    }
  }

#pragma unroll
  for (int rb = 0; rb < 2; ++rb) {
    const int rbase = (wrg * 2 + rb) * 16 + ((lane >> 4) << 2);
#pragma unroll
    for (int cf = 0; cf < 4; ++cf) {
      const int col = wc * 64 + cf * 16 + (lane & 15);
      const float bv = be0b[col];
#pragma unroll
      for (int r = 0; r < 4; ++r)
        atomicAdd(&agg[(long)sDst[rbase + r] * HD + col], acc[rb][cf][r] + bv);
    }
  }
}

// ---------------------------------------------------------------------------
// Fused conv[0] edge MLP + predictor, ea1 algebraically folded out:
//   h0  = relu(Ps[s]+Pd[d]+ea@W6+b0)
//   h1  = relu(h0@WA + P1s[s]+P1d[d]+bA)     WA = We0b@WeE, bA = be0b@WeE+be1a
//   t   = h0@WB                              WB = We0b@Wp1  (reg-resident)
//   z   = h1@Wc + t + bc                     Wc = We1b@Wp1, bc=(be1b+be0b)@Wp1+bp1
//   out = leaky_relu(z)@Wp2 + bp2
// 512 threads, 64 edges/block, 3 GEMM-equivalents, ~5 barriers total.
// ---------------------------------------------------------------------------
__global__ __launch_bounds__(512, 4)
void edge_pred(const int* __restrict__ ei, const float* __restrict__ eattr,
               const float* __restrict__ Ps, const float* __restrict__ Pd,
               const float* __restrict__ W6, const float* __restrict__ b0,
               const float* __restrict__ P1s, const float* __restrict__ P1d,
               const ushort* __restrict__ pWA, const ushort* __restrict__ pWB,
               const ushort* __restrict__ pWc,
               const float* __restrict__ bA, const float* __restrict__ bc,
               const float* __restrict__ Wp2, const float* __restrict__ bp2,
               float* __restrict__ out)
{
  __shared__ ushort Ah[64 * 256];
  __shared__ ushort Al[64 * 256];
  __shared__ float  sW6[6 * 256];
  __shared__ float  sEA[64 * 6];
  __shared__ float  sB0[256];
  __shared__ float  sOut[64];
  __shared__ int    sSrc[64], sDst[64];
  const int tid = threadIdx.x;
  const long e0 = (long)blockIdx.x * 64;

  if (tid < 64) {
    sDst[tid] = ei[N_EDGES + e0 + tid];
    sOut[tid] = bp2[0];
  } else if (tid < 128) {
    sSrc[tid - 64] = ei[e0 + tid - 64];
  }
  if (tid < 96)  *(float4*)&sEA[tid * 4] = *(const float4*)&eattr[e0 * 6 + tid * 4];
  if (tid < 384) *(float4*)&sW6[tid * 4] = *(const float4*)&W6[tid * 4];
  if (tid < 64)  *(float4*)&sB0[tid * 4] = *(const float4*)&b0[tid * 4];
  __syncthreads();

  build_h0(tid, Ps, Pd, sEA, sW6, sB0, sSrc, sDst, Ah, Al);
  __syncthreads();

  const int lane = tid & 63, wid = tid >> 6;
  const int wc = wid & 3, wrg = wid >> 2;
  const bf16x8* pAH = (const bf16x8*)pWA;
  const bf16x8* pAL = (const bf16x8*)(pWA + 65536);
  const bf16x8* pBH = (const bf16x8*)pWB;
  const bf16x8* pBL = (const bf16x8*)(pWB + 65536);
  const bf16x8* pCH = (const bf16x8*)pWc;
  const bf16x8* pCL = (const bf16x8*)(pWc + 65536);

  // ---- GEMM1 dual: acc1 = h0@WA, accT = h0@WB ----
  f32x4 acc1[2][4], accT[2][4];
#pragma unroll
  for (int rb = 0; rb < 2; ++rb)
#pragma unroll
    for (int cf = 0; cf < 4; ++cf) {
      acc1[rb][cf] = (f32x4){0.f, 0.f, 0.f, 0.f};
      accT[rb][cf] = (f32x4){0.f, 0.f, 0.f, 0.f};
    }

#pragma unroll 2
  for (int s = 0; s < 8; ++s) {
    bf16x8 ah[2], al[2];
#pragma unroll
    for (int rb = 0; rb < 2; ++rb)
      load_afrag(Ah, Al, (wrg * 2 + rb) * 16 + (lane & 15), s, lane, ah[rb], al[rb]);
#pragma unroll
    for (int cf = 0; cf < 4; ++cf) {
      const int slot = s * 1024 + (wc * 4 + cf) * 64 + lane;
      bf16x8 b1h = pAH[slot];
      bf16x8 b1l = pAL[slot];
      bf16x8 b2h = pBH[slot];
      bf16x8 b2l = pBL[slot];
#pragma unroll
      for (int rb = 0; rb < 2; ++rb) {
        acc1[rb][cf] = MFMA16(al[rb], b1h, acc1[rb][cf], 0, 0, 0);
        acc1[rb][cf] = MFMA16(ah[rb], b1l, acc1[rb][cf], 0, 0, 0);
        acc1[rb][cf] = MFMA16(ah[rb], b1h, acc1[rb][cf], 0, 0, 0);
        accT[rb][cf] = MFMA16(al[rb], b2h, accT[rb][cf], 0, 0, 0);
        accT[rb][cf] = MFMA16(ah[rb], b2l, accT[rb][cf], 0, 0, 0);
        accT[rb][cf] = MFMA16(ah[rb], b2h, accT[rb][cf], 0, 0, 0);
      }
    }
  }
  __syncthreads();   // all h0 reads complete before overwriting the A tile

  // ---- epilogue1: h1 = relu(acc1 + P1s[s]+P1d[d]+bA) -> A tile ----
#pragma unroll
  for (int rb = 0; rb < 2; ++rb) {
    const int rbase = (wrg * 2 + rb) * 16 + ((lane >> 4) << 2);
#pragma unroll
    for (int cf = 0; cf < 4; ++cf) {
      const int col = wc * 64 + cf * 16 + (lane & 15);
      const float bv = bA[col];
#pragma unroll
      for (int r = 0; r < 4; ++r) {
        const int row = rbase + r;
        float v = acc1[rb][cf][r] + P1s[(long)sSrc[row] * HD + col]
                                  + P1d[(long)sDst[row] * HD + col] + bv;
        write_split(Ah, Al, row, col, fmaxf(v, 0.f));
      }
    }
  }
  __syncthreads();

  // ---- GEMM2: accZ = h1@Wc ----
  f32x4 accZ[2][4];
#pragma unroll
  for (int rb = 0; rb < 2; ++rb)
#pragma unroll
    for (int cf = 0; cf < 4; ++cf) accZ[rb][cf] = (f32x4){0.f, 0.f, 0.f, 0.f};

#pragma unroll 2
  for (int s = 0; s < 8; ++s) {
    bf16x8 ah[2], al[2];
#pragma unroll
    for (int rb = 0; rb < 2; ++rb)
      load_afrag(Ah, Al, (wrg * 2 + rb) * 16 + (lane & 15), s, lane, ah[rb], al[rb]);
#pragma unroll
    for (int cf = 0; cf < 4; ++cf) {
      const int slot = s * 1024 + (wc * 4 + cf) * 64 + lane;
      bf16x8 bh = pCH[slot];
      bf16x8 bl = pCL[slot];
#pragma unroll
      for (int rb = 0; rb < 2; ++rb) {
        accZ[rb][cf] = MFMA16(al[rb], bh, accZ[rb][cf], 0, 0, 0);
        accZ[rb][cf] = MFMA16(ah[rb], bl, accZ[rb][cf], 0, 0, 0);
        accZ[rb][cf] = MFMA16(ah[rb], bh, accZ[rb][cf], 0, 0, 0);
      }
    }
  }

  // ---- finale: z = accZ + accT + bc; leaky; dot Wp2; reduce ----
  float p[2][4] = {{0.f,0.f,0.f,0.f},{0.f,0.f,0.f,0.f}};
#pragma unroll
  for (int cf = 0; cf < 4; ++cf) {
    const int col = wc * 64 + cf * 16 + (lane & 15);
    const float w   = Wp2[col];
    const float bcv = bc[col];
#pragma unroll
    for (int rb = 0; rb < 2; ++rb)
#pragma unroll
      for (int r = 0; r < 4; ++r) {
        float z = accZ[rb][cf][r] + accT[rb][cf][r] + bcv;
        z = z > 0.f ? z : 0.01f * z;
        p[rb][r] += z * w;
      }
  }
#pragma unroll
  for (int rb = 0; rb < 2; ++rb)
#pragma unroll
    for (int r = 0; r < 4; ++r) {
      p[rb][r] += __shfl_xor(p[rb][r], 1);
      p[rb][r] += __shfl_xor(p[rb][r], 2);
      p[rb][r] += __shfl_xor(p[rb][r], 4);
      p[rb][r] += __shfl_xor(p[rb][r], 8);
    }
  if ((lane & 15) == 0) {
#pragma unroll
    for (int rb = 0; rb < 2; ++rb) {
      const int rbase = (wrg * 2 + rb) * 16 + ((lane >> 4) << 2);
#pragma unroll
      for (int r = 0; r < 4; ++r) atomicAdd(&sOut[rbase + r], p[rb][r]);
    }
  }
  __syncthreads();
  if (tid < 64) out[e0 + tid] = sOut[tid];
}

// ---------------------------------------------------------------------------
extern "C" void kernel_launch(void* const* d_in, const int* in_sizes, int n_in,
                              void* d_out, int out_size, void* d_ws, size_t ws_size,
                              hipStream_t stream)
{
  const float* x     = (const float*)d_in[0];
  const int*   ei    = (const int*)d_in[1];
  const float* eattr = (const float*)d_in[2];
  const float* We0a  = (const float*)d_in[3];
  const float* be0a  = (const float*)d_in[4];
  const float* We0b  = (const float*)d_in[5];
  const float* be0b  = (const float*)d_in[6];
  const float* Wn0a  = (const float*)d_in[7];
  const float* bn0a  = (const float*)d_in[8];
  const float* Wn0b  = (const float*)d_in[9];
  const float* bn0b  = (const float*)d_in[10];
  const float* We1a  = (const float*)d_in[11];
  const float* be1a  = (const float*)d_in[12];
  const float* We1b  = (const float*)d_in[13];
  const float* be1b  = (const float*)d_in[14];
  // d_in[15..18] dead (conv[0] node MLP never reaches the output)
  const float* Wp1   = (const float*)d_in[19];
  const float* bp1   = (const float*)d_in[20];
  const float* Wp2   = (const float*)d_in[21];
  const float* bp2   = (const float*)d_in[22];
  float* out = (float*)d_out;
  float* ws  = (float*)d_ws;

  float* P_s  = ws;
  float* P_d  = ws + OFF_PD;
  float* bufA = ws + OFF_BA;
  float* bufB = ws + OFF_BB;
  float* bufC = ws + OFF_BC;
  float* deg  = ws + OFF_DEG;
  float* bcB  = ws + OFF_BCV;
  float* bAB  = ws + OFF_BAV;
  ushort* pW0 = (ushort*)(ws + OFF_PW0);

  // composite-weight area inside bufB (dead after P1s/P1d are produced)
  float*  WAf = ws + OFF_BB;
  float*  WBf = ws + OFF_BB + 65536;
  float*  WcF = ws + OFF_BB + 131072;
  ushort* pWA = (ushort*)(ws + OFF_BB + 196608);
  ushort* pWB = (ushort*)(ws + OFF_BB + 262144);
  ushort* pWc = (ushort*)(ws + OFF_BB + 327680);

  const float* W6  = We0a + 1024 * HD;   // edge_attr rows of We0a
  const float* WeE = We1a + 512 * HD;    // ea1 rows of We1a

  // zero agg + deg (contiguous)
  hipMemsetAsync(bufC, 0, (2560000 + 10000) * sizeof(float), stream);

  const int ngrid = (N_NODES + 63) / 64;   // 157
  const int egrid = N_EDGES / 64;          // 5000

  // node projections + conv_in prep
  node_gemm<<<ngrid, 256, 0, stream>>>(x, 512, nullptr, 0, nullptr, We0a,            nullptr, P_s, N_NODES, 0);
  node_gemm<<<ngrid, 256, 0, stream>>>(x, 512, nullptr, 0, nullptr, We0a + 512 * HD, nullptr, P_d, N_NODES, 0);
  prep_split<<<32, 256, 0, stream>>>(We0b, pW0, pW0 + 65536);
  bias_fold_k<<<1, 256, 0, stream>>>(be1b, be0b, Wp1, bp1, bcB);   // bc'
  bias_fold_k<<<1, 256, 0, stream>>>(be0b, nullptr, WeE, be1a, bAB); // bA

  // conv_in edge stage -> agg, deg
  edge_conv_in<<<egrid, 512, 0, stream>>>(ei, eattr, P_s, P_d, W6, be0a,
                                          pW0, be0b, bufC, deg);
  rdeg_k<<<(N_NODES + 255) / 256, 256, 0, stream>>>(deg);

  // node pipeline
  node_gemm<<<ngrid, 256, 0, stream>>>(x, 512, bufC, 256, deg, Wn0a, bn0a, bufA, N_NODES, 1);          // t1
  node_gemm<<<ngrid, 256, 0, stream>>>(bufA, 256, nullptr, 0, nullptr, Wn0b, bn0b, bufB, N_NODES, 0);  // x1
  node_gemm<<<ngrid, 256, 0, stream>>>(bufB, 256, nullptr, 0, nullptr, We1a,            nullptr, bufA, N_NODES, 0); // P1s
  node_gemm<<<ngrid, 256, 0, stream>>>(bufB, 256, nullptr, 0, nullptr, We1a + 256 * HD, nullptr, bufC, N_NODES, 0); // P1d

  // composite weights (bufB/x1 now dead): WA=We0b@WeE, WB=We0b@Wp1, Wc=We1b@Wp1
  node_gemm<<<4, 256, 0, stream>>>(We0b, 256, nullptr, 0, nullptr, WeE, nullptr, WAf, 256, 0);
  node_gemm<<<4, 256, 0, stream>>>(We0b, 256, nullptr, 0, nullptr, Wp1, nullptr, WBf, 256, 0);
  node_gemm<<<4, 256, 0, stream>>>(We1b, 256, nullptr, 0, nullptr, Wp1, nullptr, WcF, 256, 0);
  prep_split<<<32, 256, 0, stream>>>(WAf, pWA, pWA + 65536);
  prep_split<<<32, 256, 0, stream>>>(WBf, pWB, pWB + 65536);
  prep_split<<<32, 256, 0, stream>>>(WcF, pWc, pWc + 65536);

  // fused conv[0] edge MLP + predictor
  edge_pred<<<egrid, 512, 0, stream>>>(ei, eattr, P_s, P_d, W6, be0a,
      bufA, bufC, pWA, pWB, pWc, bAB, bcB, Wp2, bp2, out);
}